// Round 18
// baseline (273.564 us; speedup 1.0000x reference)
//
#include <hip/hip_runtime.h>
#include <math.h>

#define NEG_SLOPE 0.2f
#define NBUK_MAX 512    // LDS capacity for bucket counters (buckets of 256 dsts; NBUK=391)

typedef float v4f __attribute__((ext_vector_type(4)));

// ---------------- K_A: histB (blocks 0..B2) UNION argmax (rest) ----------------
// bucket = dst >> 8 (256 dsts per bucket)
template <int B2>
__global__ void __launch_bounds__(1024)
k_histarg(const float* __restrict__ x, const int* __restrict__ edst, int E,
          int* __restrict__ histT, int NBUK, int* __restrict__ idx, int N, int V) {
    __shared__ int sh[NBUK_MAX];
    int t = threadIdx.x;
    if ((int)blockIdx.x < B2) {
        int b = blockIdx.x;
        for (int k = t; k < NBUK; k += 1024) sh[k] = 0;
        __syncthreads();
        long long ebeg = (long long)b * E / B2, eend = (long long)(b + 1) * E / B2;
        for (long long i = ebeg + t; i < eend; i += 1024)
            atomicAdd(&sh[edst[i] >> 8], 1);
        __syncthreads();
        for (int k = t; k < NBUK; k += 1024) histT[(long long)k * B2 + b] = sh[k];
    } else {
        int node = ((int)blockIdx.x - B2) * 32 + (t >> 5);
        int lane = t & 31;
        if (node >= N) return;
        const v4f* row = (const v4f*)(x + (long long)node * V);
        float bv = -INFINITY;
        int bi = 0x7fffffff;
        int nq = V >> 2;
        for (int q = lane; q < nq; q += 32) {
            v4f v = row[q];
            int base = q << 2;
            if (v.x > bv || (v.x == bv && base     < bi)) { bv = v.x; bi = base;     }
            if (v.y > bv || (v.y == bv && base + 1 < bi)) { bv = v.y; bi = base + 1; }
            if (v.z > bv || (v.z == bv && base + 2 < bi)) { bv = v.z; bi = base + 2; }
            if (v.w > bv || (v.w == bv && base + 3 < bi)) { bv = v.w; bi = base + 3; }
        }
        for (int off = 16; off > 0; off >>= 1) {
            float ov = __shfl_down(bv, off, 32);
            int   oi = __shfl_down(bi, off, 32);
            if (ov > bv || (ov == bv && oi < bi)) { bv = ov; bi = oi; }
        }
        if (lane == 0) idx[node] = bi;
    }
}

// ---------------- K_B: scan1 (blocks 0..NB_SCAN) UNION layer-1 transform (rest) ----------------
template <int FIN, int FOUT>
__global__ void __launch_bounds__(256)
k_scan_tr(const int* __restrict__ vals, int* __restrict__ excl, int* __restrict__ bsums, int M,
          const float* __restrict__ emb, const int* __restrict__ idx,
          const float* __restrict__ W, const float* __restrict__ a_src,
          const float* __restrict__ a_dst, _Float16* __restrict__ h_t,
          float* __restrict__ asrc, float* __restrict__ adst, int N, int NB_SCAN) {
    __shared__ int s[256];
    __shared__ float sW[FIN * FOUT];
    __shared__ float sa[FOUT], sd[FOUT];
    int t = threadIdx.x;
    if ((int)blockIdx.x < NB_SCAN) {
        int i = blockIdx.x * 256 + t;
        int v = (i < M) ? vals[i] : 0;
        s[t] = v;
        __syncthreads();
        for (int off = 1; off < 256; off <<= 1) {
            int a = (t >= off) ? s[t - off] : 0;
            __syncthreads();
            s[t] += a;
            __syncthreads();
        }
        if (i < M) excl[i] = s[t] - v;
        if (t == 255) bsums[blockIdx.x] = s[255];
    } else {
        for (int i = t; i < FIN * FOUT; i += 256) sW[i] = W[i];
        if (t < FOUT) { sa[t] = a_src[t]; sd[t] = a_dst[t]; }
        __syncthreads();
        int n = ((int)blockIdx.x - NB_SCAN) * 256 + t;
        if (n >= N) return;
        float acc[FOUT];
#pragma unroll
        for (int f = 0; f < FOUT; f++) acc[f] = 0.f;
        const float* hr = emb + (long long)idx[n] * FIN;
        for (int k = 0; k < FIN; k++) {
            float v = hr[k];
#pragma unroll
            for (int f = 0; f < FOUT; f++) acc[f] += v * sW[k * FOUT + f];
        }
        float s1 = 0.f, s2 = 0.f;
        _Float16 hh[16];
#pragma unroll
        for (int f = 0; f < 16; f++) hh[f] = (_Float16)0.f;
#pragma unroll
        for (int f = 0; f < FOUT; f++) {
            hh[f] = (_Float16)acc[f];
            s1 += acc[f] * sa[f];
            s2 += acc[f] * sd[f];
        }
        uint4* dst = (uint4*)(h_t + (long long)n * 16);
        dst[0] = ((uint4*)hh)[0];
        dst[1] = ((uint4*)hh)[1];
        asrc[n] = s1;
        adst[n] = s2;
    }
}

// ---------------- scan2: exclusive scan of chunk sums (capacity 2048) ----------------
__global__ void k_scan2(int* __restrict__ bsums, int nb) {
    __shared__ int s[2048];
    int i = threadIdx.x;
    int v0 = (i < nb) ? bsums[i] : 0;
    int v1 = (i + 1024 < nb) ? bsums[i + 1024] : 0;
    s[i] = v0;
    s[i + 1024] = v1;
    __syncthreads();
    for (int off = 1; off < 2048; off <<= 1) {
        int a0 = (i >= off) ? s[i - off] : 0;
        int a1 = (i + 1024 >= off) ? s[i + 1024 - off] : 0;
        __syncthreads();
        s[i] += a0;
        s[i + 1024] += a1;
        __syncthreads();
    }
    if (i < nb) bsums[i] = s[i] - v0;
    if (i + 1024 < nb) bsums[i + 1024] = s[i + 1024] - v1;
}

// ---------------- scatB: exact-slot scatter; LDS cursors; 2 blocks/CU ----------------
// Correct chunk indexing: global offset of histT element e is sexcl[e] + bsums[e>>8].
template <int B2>
__global__ void __launch_bounds__(1024)
k_scatB(const int* __restrict__ esrc, const int* __restrict__ edst, int E,
        const int* __restrict__ sexcl, const int* __restrict__ bsums,
        int* __restrict__ tmp, int NBUK) {
    __shared__ int cur[NBUK_MAX];
    int t = threadIdx.x, b = blockIdx.x;
    for (int k = t; k < NBUK; k += 1024) {
        long long e = (long long)k * B2 + b;
        cur[k] = sexcl[e] + bsums[e >> 8];
    }
    __syncthreads();
    long long ebeg = (long long)b * E / B2, eend = (long long)(b + 1) * E / B2;
    for (long long i = ebeg + t; i < eend; i += 1024) {
        int d = edst[i];
        int pos = atomicAdd(&cur[d >> 8], 1);
        tmp[pos] = ((d & 255) << 17) | esrc[i];   // src < 2^17
    }
}

// ---------------- binB: 256-dst buckets; block-scan; bin to exact csr slots ----------------
template <int B2>
__global__ void __launch_bounds__(256)
k_binB(const int* __restrict__ sexcl, const int* __restrict__ bsums,
       const int* __restrict__ tmp,
       int* __restrict__ rowptr, int* __restrict__ csr_src, int N, int NBUK, int E) {
    __shared__ int cnt[256];
    __shared__ int scn[256];
    __shared__ int cur[256];
    int t = threadIdx.x, b = blockIdx.x;
    long long e0i = (long long)b * B2;
    int t0 = sexcl[e0i] + bsums[e0i >> 8];
    int t1;
    if (b + 1 < NBUK) {
        long long e1i = (long long)(b + 1) * B2;
        t1 = sexcl[e1i] + bsums[e1i >> 8];
    } else {
        t1 = E;
    }
    cnt[t] = 0;
    __syncthreads();
    for (int i = t0 + t; i < t1; i += 256) atomicAdd(&cnt[tmp[i] >> 17], 1);
    __syncthreads();
    int v = cnt[t];
    scn[t] = v;
    __syncthreads();
    for (int off = 1; off < 256; off <<= 1) {
        int a = (t >= off) ? scn[t - off] : 0;
        __syncthreads();
        scn[t] += a;
        __syncthreads();
    }
    int base = t0 + scn[t] - v;
    int d = (b << 8) + t;
    if (d < N) rowptr[d] = base;
    cur[t] = base;
    if (d == N - 1) rowptr[N] = E;
    __syncthreads();
    for (int i = t0 + t; i < t1; i += 256) {
        int p = tmp[i];
        int pos = atomicAdd(&cur[p >> 17], 1);
        csr_src[pos] = p & 0x1FFFF;
    }
}

// ---------------- GAT aggregation core (pipelined; 4 rotating accumulators) ----------------
template <typename EPI>
__device__ __forceinline__ void gat_core(const int* __restrict__ rowptr,
                                         const int* __restrict__ csr_src,
                                         const float* __restrict__ asrc,
                                         const float* __restrict__ adst,
                                         const _Float16* __restrict__ h_t,
                                         int N, int grp, int lane, EPI epilogue) {
    int d = grp;
    int r0 = rowptr[d], r1 = rowptr[d + 1];
    float ad = adst[d];

    float e0 = asrc[d] + ad;
    e0 = (e0 >= 0.f) ? e0 : NEG_SLOPE * e0;
    float p0 = __expf(e0);
    float ac0 = p0 * (float)h_t[(long long)d * 16 + lane];
    float ac1 = 0.f, ac2 = 0.f, ac3 = 0.f;     // dep chain 16 -> 4
    float psum = (lane == 0) ? p0 : 0.f;

    int j = r0;
    if (j < r1) {
        int myj = j + lane;
        bool valid = myj < r1;
        int s = valid ? csr_src[myj] : d;
        float a = asrc[s];
        while (true) {
            int jn = j + 16;
            int s2 = d; float a2 = 0.f; bool validn = false;
            if (jn < r1) {
                int myjn = jn + lane;
                validn = myjn < r1;
                s2 = validn ? csr_src[myjn] : d;
                a2 = asrc[s2];
            }
            float e = a + ad;
            e = (e >= 0.f) ? e : NEG_SLOPE * e;
            float p = valid ? __expf(e) : 0.f;
            psum += p;
#pragma unroll
            for (int k = 0; k < 16; k += 4) {
                float pk0 = __shfl(p, k + 0, 16);
                int   sk0 = __shfl(s, k + 0, 16);
                float pk1 = __shfl(p, k + 1, 16);
                int   sk1 = __shfl(s, k + 1, 16);
                float pk2 = __shfl(p, k + 2, 16);
                int   sk2 = __shfl(s, k + 2, 16);
                float pk3 = __shfl(p, k + 3, 16);
                int   sk3 = __shfl(s, k + 3, 16);
                ac0 += pk0 * (float)h_t[(long long)sk0 * 16 + lane];
                ac1 += pk1 * (float)h_t[(long long)sk1 * 16 + lane];
                ac2 += pk2 * (float)h_t[(long long)sk2 * 16 + lane];
                ac3 += pk3 * (float)h_t[(long long)sk3 * 16 + lane];
            }
            if (jn >= r1) break;
            j = jn; s = s2; a = a2; valid = validn;
        }
    }
    float acc = (ac0 + ac1) + (ac2 + ac3);
    for (int off = 8; off > 0; off >>= 1) psum += __shfl_xor(psum, off, 16);
    epilogue(d, acc / fmaxf(psum, 1e-16f));
}

// gat + bias/relu + NEXT-layer transform fused in-register
template <int FN>
__global__ void k_gat_ft(const int* __restrict__ rowptr, const int* __restrict__ csr_src,
                         const float* __restrict__ asrc, const float* __restrict__ adst,
                         const _Float16* __restrict__ h_t, const float* __restrict__ bias,
                         const float* __restrict__ Wn, const float* __restrict__ an_src,
                         const float* __restrict__ an_dst,
                         _Float16* __restrict__ h_next, float* __restrict__ asrc_n,
                         float* __restrict__ adst_n, int N) {
    __shared__ float sW[16 * FN];
    __shared__ float sa[FN], sd[FN], sb[16];
    for (int i = threadIdx.x; i < 16 * FN; i += blockDim.x) sW[i] = Wn[i];
    if (threadIdx.x < FN) { sa[threadIdx.x] = an_src[threadIdx.x]; sd[threadIdx.x] = an_dst[threadIdx.x]; }
    if (threadIdx.x < 16) sb[threadIdx.x] = bias[threadIdx.x];
    __syncthreads();

    int grp  = (blockIdx.x * blockDim.x + threadIdx.x) >> 4;
    int lane = threadIdx.x & 15;
    if (grp >= N) return;

    gat_core(rowptr, csr_src, asrc, adst, h_t, N, grp, lane,
        [&](int d, float v) {
            v = fmaxf(v + sb[lane], 0.f);
            float acc2 = 0.f;
#pragma unroll
            for (int k = 0; k < 16; k++) {
                float vk = __shfl(v, k, 16);
                if (lane < FN) acc2 += vk * sW[k * FN + lane];
            }
            float c1 = (lane < FN) ? acc2 * sa[lane] : 0.f;
            float c2 = (lane < FN) ? acc2 * sd[lane] : 0.f;
            for (int off = 8; off > 0; off >>= 1) {
                c1 += __shfl_xor(c1, off, 16);
                c2 += __shfl_xor(c2, off, 16);
            }
            h_next[(long long)d * 16 + lane] = (_Float16)((lane < FN) ? acc2 : 0.f);
            if (lane == 0) { asrc_n[d] = c1; adst_n[d] = c2; }
        });
}

// final gat: fp32 out rows of width FOUT (b3 folded into pool)
template <int FOUT>
__global__ void k_gat_last(const int* __restrict__ rowptr, const int* __restrict__ csr_src,
                           const float* __restrict__ asrc, const float* __restrict__ adst,
                           const _Float16* __restrict__ h_t, float* __restrict__ out, int N) {
    int grp  = (blockIdx.x * blockDim.x + threadIdx.x) >> 4;
    int lane = threadIdx.x & 15;
    if (grp >= N) return;
    gat_core(rowptr, csr_src, asrc, adst, h_t, N, grp, lane,
        [&](int d, float v) {
            if (lane < FOUT) out[(long long)d * FOUT + lane] = v;
        });
}

// ---------------- pool + softmax ----------------
__global__ void k_pool(const float* __restrict__ h3, const int* __restrict__ batch,
                       const float* __restrict__ b3, float* __restrict__ out, int N, int C) {
    int g = blockIdx.x;
    int lo = 0, hi = N;
    while (lo < hi) { int mid = (lo + hi) >> 1; if (batch[mid] < g) lo = mid + 1; else hi = mid; }
    int start = lo;
    hi = N;
    while (lo < hi) { int mid = (lo + hi) >> 1; if (batch[mid] < g + 1) lo = mid + 1; else hi = mid; }
    int end = lo;

    float sum[16];
    for (int f = 0; f < C; f++) sum[f] = 0.f;
    for (int n = start + threadIdx.x; n < end; n += blockDim.x) {
        const float* r = h3 + (long long)n * C;
        for (int f = 0; f < C; f++) sum[f] += r[f];
    }
    __shared__ float red[256 * 16];
    for (int f = 0; f < C; f++) red[threadIdx.x * 16 + f] = sum[f];
    __syncthreads();
    for (int str = blockDim.x / 2; str > 0; str >>= 1) {
        if ((int)threadIdx.x < str)
            for (int f = 0; f < C; f++) red[threadIdx.x * 16 + f] += red[(threadIdx.x + str) * 16 + f];
        __syncthreads();
    }
    if (threadIdx.x == 0) {
        float cnt = fmaxf((float)(end - start), 1.f);
        float vals[16];
        float mx = -INFINITY;
        for (int f = 0; f < C; f++) { vals[f] = red[f] / cnt + b3[f]; mx = fmaxf(mx, vals[f]); }
        float se = 0.f;
        for (int f = 0; f < C; f++) { vals[f] = __expf(vals[f] - mx); se += vals[f]; }
        for (int f = 0; f < C; f++) out[(long long)g * C + f] = vals[f] / se;
    }
}

extern "C" void kernel_launch(void* const* d_in, const int* in_sizes, int n_in,
                              void* d_out, int out_size, void* d_ws, size_t ws_size,
                              hipStream_t stream) {
    const float* x    = (const float*)d_in[0];
    const int*   eidx = (const int*)d_in[1];
    const int*   batch= (const int*)d_in[2];
    const float* emb  = (const float*)d_in[3];
    const float* W1   = (const float*)d_in[4];
    const float* as1  = (const float*)d_in[5];
    const float* ad1  = (const float*)d_in[6];
    const float* b1   = (const float*)d_in[7];
    const float* W2   = (const float*)d_in[8];
    const float* as2  = (const float*)d_in[9];
    const float* ad2  = (const float*)d_in[10];
    const float* b2   = (const float*)d_in[11];
    const float* W3   = (const float*)d_in[12];
    const float* as3  = (const float*)d_in[13];
    const float* ad3  = (const float*)d_in[14];
    const float* b3   = (const float*)d_in[15];

    const int H = in_sizes[5];          // 16
    const int C = in_sizes[13];         // 10
    const int D = in_sizes[4] / H;      // 50
    const int V = in_sizes[3] / D;      // 128
    const int N = in_sizes[0] / V;      // 100000
    const int E = in_sizes[1] / 2;      // 1600000
    const int G = out_size / C;         // 512
    const int* esrc = eidx;
    const int* edst = eidx + E;
    const int NBUK = (N + 255) >> 8;    // 391 buckets of 256 dsts
    constexpr int B2 = 512;             // scatter blocks: 2 blocks/CU -> 32 waves/CU
    const int M = NBUK * B2;            // histT elements (200K)

    char* w = (char*)d_ws;
    auto carve = [&](size_t bytes) {
        char* p = w;
        w += (bytes + 255) & ~(size_t)255;
        return p;
    };
    float*     as_a    = (float*)carve((size_t)N * 4);
    float*     ad_a    = (float*)carve((size_t)N * 4);
    float*     as_b    = (float*)carve((size_t)N * 4);
    float*     ad_b    = (float*)carve((size_t)N * 4);
    int*       idx     = (int*)carve((size_t)N * 4);
    int*       rowptr  = (int*)carve((size_t)(N + 1) * 4);
    int*       csr_src = (int*)carve((size_t)E * 4);
    int*       histT   = (int*)carve((size_t)M * 4);
    int*       sexcl   = (int*)carve((size_t)M * 4);
    int*       bsums   = (int*)carve(2048 * 4);
    _Float16*  hTa     = (_Float16*)carve((size_t)N * 16 * 2);
    _Float16*  hTb     = (_Float16*)carve((size_t)N * 16 * 2);
    size_t zone_bytes = ((size_t)E * 4 > (size_t)N * C * 4) ? (size_t)E * 4 : (size_t)N * C * 4;
    char*  zone = carve(zone_bytes);
    float* X0  = (float*)zone;
    int*   tmp = (int*)zone;
    (void)ws_size; (void)n_in;

    const int BT = 256;
    dim3 blk(BT);
    int gGat  = (N * 16 + BT - 1) / BT;     // 16 lanes per dst
    int nb2   = (M + 255) / 256;            // scan blocks over histT (782 <= 2048)
    int gArg  = (N + 31) / 32;              // argmax blocks (32 nodes per 1024-thr block)
    int gTr   = (N + BT - 1) / BT;          // transform blocks

    // ---- K_A: histB + argmax in one launch ----
    k_histarg<B2><<<B2 + gArg, dim3(1024), 0, stream>>>(x, edst, E, histT, NBUK, idx, N, V);

    // ---- K_B: scan1 + layer-1 transform in one launch ----
    k_scan_tr<50, 16><<<nb2 + gTr, blk, 0, stream>>>(histT, sexcl, bsums, M,
                                                     emb, idx, W1, as1, ad1, hTa, as_a, ad_a, N, nb2);
    k_scan2<<<1, 1024, 0, stream>>>(bsums, nb2);

    // ---- scatter + bin ----
    k_scatB<B2><<<B2, dim3(1024), 0, stream>>>(esrc, edst, E, sexcl, bsums, tmp, NBUK);
    k_binB<B2><<<NBUK, blk, 0, stream>>>(sexcl, bsums, tmp, rowptr, csr_src, N, NBUK, E);

    // ---- gat1 (+b1,relu) fused with transform2 -> hTb, a_b ----
    k_gat_ft<16><<<gGat, blk, 0, stream>>>(rowptr, csr_src, as_a, ad_a, hTa, b1,
                                           W2, as2, ad2, hTb, as_b, ad_b, N);

    // ---- gat2 (+b2,relu) fused with transform3 -> hTa, a_a ----
    k_gat_ft<10><<<gGat, blk, 0, stream>>>(rowptr, csr_src, as_b, ad_b, hTb, b2,
                                           W3, as3, ad3, hTa, as_a, ad_a, N);

    // ---- gat3 -> X0 (N x 10 fp32) ----
    k_gat_last<10><<<gGat, blk, 0, stream>>>(rowptr, csr_src, as_a, ad_a, hTa, X0, N);

    // ---- pool + softmax ----
    k_pool<<<G, blk, 0, stream>>>(X0, batch, b3, (float*)d_out, N, C);
}

// Round 19
// 265.448 us; speedup vs baseline: 1.0306x; 1.0306x over previous
//
#include <hip/hip_runtime.h>
#include <math.h>

#define NEG_SLOPE 0.2f
#define NBUK_MAX 512    // LDS capacity for bucket counters (buckets of 256 dsts; NBUK=391)

typedef float v4f __attribute__((ext_vector_type(4)));

// ---------------- K_A: histB (blocks 0..B2) UNION argmax (rest) ----------------
// bucket = dst >> 8 (256 dsts per bucket)
template <int B2>
__global__ void __launch_bounds__(1024)
k_histarg(const float* __restrict__ x, const int* __restrict__ edst, int E,
          int* __restrict__ histT, int NBUK, int* __restrict__ idx, int N, int V) {
    __shared__ int sh[NBUK_MAX];
    int t = threadIdx.x;
    if ((int)blockIdx.x < B2) {
        int b = blockIdx.x;
        for (int k = t; k < NBUK; k += 1024) sh[k] = 0;
        __syncthreads();
        long long ebeg = (long long)b * E / B2, eend = (long long)(b + 1) * E / B2;
        for (long long i = ebeg + t; i < eend; i += 1024)
            atomicAdd(&sh[edst[i] >> 8], 1);
        __syncthreads();
        for (int k = t; k < NBUK; k += 1024) histT[(long long)k * B2 + b] = sh[k];
    } else {
        int node = ((int)blockIdx.x - B2) * 32 + (t >> 5);
        int lane = t & 31;
        if (node >= N) return;
        const v4f* row = (const v4f*)(x + (long long)node * V);
        float bv = -INFINITY;
        int bi = 0x7fffffff;
        int nq = V >> 2;
        for (int q = lane; q < nq; q += 32) {
            v4f v = row[q];
            int base = q << 2;
            if (v.x > bv || (v.x == bv && base     < bi)) { bv = v.x; bi = base;     }
            if (v.y > bv || (v.y == bv && base + 1 < bi)) { bv = v.y; bi = base + 1; }
            if (v.z > bv || (v.z == bv && base + 2 < bi)) { bv = v.z; bi = base + 2; }
            if (v.w > bv || (v.w == bv && base + 3 < bi)) { bv = v.w; bi = base + 3; }
        }
        for (int off = 16; off > 0; off >>= 1) {
            float ov = __shfl_down(bv, off, 32);
            int   oi = __shfl_down(bi, off, 32);
            if (ov > bv || (ov == bv && oi < bi)) { bv = ov; bi = oi; }
        }
        if (lane == 0) idx[node] = bi;
    }
}

// ---------------- K_B: scan1 (blocks 0..NB_SCAN) UNION layer-1 transform (rest) ----------------
template <int FIN, int FOUT>
__global__ void __launch_bounds__(256)
k_scan_tr(const int* __restrict__ vals, int* __restrict__ excl, int* __restrict__ bsums, int M,
          const float* __restrict__ emb, const int* __restrict__ idx,
          const float* __restrict__ W, const float* __restrict__ a_src,
          const float* __restrict__ a_dst, _Float16* __restrict__ h_t,
          float* __restrict__ asrc, float* __restrict__ adst, int N, int NB_SCAN) {
    __shared__ int s[256];
    __shared__ float sW[FIN * FOUT];
    __shared__ float sa[FOUT], sd[FOUT];
    int t = threadIdx.x;
    if ((int)blockIdx.x < NB_SCAN) {
        int i = blockIdx.x * 256 + t;
        int v = (i < M) ? vals[i] : 0;
        s[t] = v;
        __syncthreads();
        for (int off = 1; off < 256; off <<= 1) {
            int a = (t >= off) ? s[t - off] : 0;
            __syncthreads();
            s[t] += a;
            __syncthreads();
        }
        if (i < M) excl[i] = s[t] - v;
        if (t == 255) bsums[blockIdx.x] = s[255];
    } else {
        for (int i = t; i < FIN * FOUT; i += 256) sW[i] = W[i];
        if (t < FOUT) { sa[t] = a_src[t]; sd[t] = a_dst[t]; }
        __syncthreads();
        int n = ((int)blockIdx.x - NB_SCAN) * 256 + t;
        if (n >= N) return;
        float acc[FOUT];
#pragma unroll
        for (int f = 0; f < FOUT; f++) acc[f] = 0.f;
        const float* hr = emb + (long long)idx[n] * FIN;
        for (int k = 0; k < FIN; k++) {
            float v = hr[k];
#pragma unroll
            for (int f = 0; f < FOUT; f++) acc[f] += v * sW[k * FOUT + f];
        }
        float s1 = 0.f, s2 = 0.f;
        _Float16 hh[16];
#pragma unroll
        for (int f = 0; f < 16; f++) hh[f] = (_Float16)0.f;
#pragma unroll
        for (int f = 0; f < FOUT; f++) {
            hh[f] = (_Float16)acc[f];
            s1 += acc[f] * sa[f];
            s2 += acc[f] * sd[f];
        }
        uint4* dst = (uint4*)(h_t + (long long)n * 16);
        dst[0] = ((uint4*)hh)[0];
        dst[1] = ((uint4*)hh)[1];
        asrc[n] = s1;
        adst[n] = s2;
    }
}

// ---------------- scan2: exclusive scan of chunk sums (capacity 2048) ----------------
__global__ void k_scan2(int* __restrict__ bsums, int nb) {
    __shared__ int s[2048];
    int i = threadIdx.x;
    int v0 = (i < nb) ? bsums[i] : 0;
    int v1 = (i + 1024 < nb) ? bsums[i + 1024] : 0;
    s[i] = v0;
    s[i + 1024] = v1;
    __syncthreads();
    for (int off = 1; off < 2048; off <<= 1) {
        int a0 = (i >= off) ? s[i - off] : 0;
        int a1 = (i + 1024 >= off) ? s[i + 1024 - off] : 0;
        __syncthreads();
        s[i] += a0;
        s[i + 1024] += a1;
        __syncthreads();
    }
    if (i < nb) bsums[i] = s[i] - v0;
    if (i + 1024 < nb) bsums[i + 1024] = s[i + 1024] - v1;
}

// ---------------- scatB: exact-slot scatter; LDS cursors; runs ~= one 64B line ----------------
// B2=256: one scan chunk per bucket -> soff(k,b) = sexcl[k*B2+b] + bsums[k]
template <int B2>
__global__ void __launch_bounds__(1024)
k_scatB(const int* __restrict__ esrc, const int* __restrict__ edst, int E,
        const int* __restrict__ sexcl, const int* __restrict__ bsums,
        int* __restrict__ tmp, int NBUK) {
    __shared__ int cur[NBUK_MAX];
    int t = threadIdx.x, b = blockIdx.x;
    for (int k = t; k < NBUK; k += 1024)
        cur[k] = sexcl[(long long)k * B2 + b] + bsums[k];
    __syncthreads();
    long long ebeg = (long long)b * E / B2, eend = (long long)(b + 1) * E / B2;
    for (long long i = ebeg + t; i < eend; i += 1024) {
        int d = edst[i];
        int pos = atomicAdd(&cur[d >> 8], 1);
        tmp[pos] = ((d & 255) << 17) | esrc[i];   // src < 2^17
    }
}

// ---------------- binB: 256-dst buckets; block-scan; bin to exact csr slots ----------------
template <int B2>
__global__ void __launch_bounds__(256)
k_binB(const int* __restrict__ sexcl, const int* __restrict__ bsums,
       const int* __restrict__ tmp,
       int* __restrict__ rowptr, int* __restrict__ csr_src, int N, int NBUK, int E) {
    __shared__ int cnt[256];
    __shared__ int scn[256];
    __shared__ int cur[256];
    int t = threadIdx.x, b = blockIdx.x;
    int t0 = sexcl[(long long)b * B2] + bsums[b];
    int t1 = (b + 1 < NBUK) ? (sexcl[(long long)(b + 1) * B2] + bsums[b + 1]) : E;
    cnt[t] = 0;
    __syncthreads();
    for (int i = t0 + t; i < t1; i += 256) atomicAdd(&cnt[tmp[i] >> 17], 1);
    __syncthreads();
    int v = cnt[t];
    scn[t] = v;
    __syncthreads();
    for (int off = 1; off < 256; off <<= 1) {
        int a = (t >= off) ? scn[t - off] : 0;
        __syncthreads();
        scn[t] += a;
        __syncthreads();
    }
    int base = t0 + scn[t] - v;
    int d = (b << 8) + t;
    if (d < N) rowptr[d] = base;
    cur[t] = base;
    if (d == N - 1) rowptr[N] = E;
    __syncthreads();
    for (int i = t0 + t; i < t1; i += 256) {
        int p = tmp[i];
        int pos = atomicAdd(&cur[p >> 17], 1);
        csr_src[pos] = p & 0x1FFFF;
    }
}

// ---------------- GAT aggregation core (pipelined) ----------------
template <typename EPI>
__device__ __forceinline__ void gat_core(const int* __restrict__ rowptr,
                                         const int* __restrict__ csr_src,
                                         const float* __restrict__ asrc,
                                         const float* __restrict__ adst,
                                         const _Float16* __restrict__ h_t,
                                         int N, int grp, int lane, EPI epilogue) {
    int d = grp;
    int r0 = rowptr[d], r1 = rowptr[d + 1];
    float ad = adst[d];

    float e0 = asrc[d] + ad;
    e0 = (e0 >= 0.f) ? e0 : NEG_SLOPE * e0;
    float p0 = __expf(e0);
    float acc  = p0 * (float)h_t[(long long)d * 16 + lane];
    float psum = (lane == 0) ? p0 : 0.f;

    int j = r0;
    if (j < r1) {
        int myj = j + lane;
        bool valid = myj < r1;
        int s = valid ? csr_src[myj] : d;
        float a = asrc[s];
        while (true) {
            int jn = j + 16;
            int s2 = d; float a2 = 0.f; bool validn = false;
            if (jn < r1) {
                int myjn = jn + lane;
                validn = myjn < r1;
                s2 = validn ? csr_src[myjn] : d;
                a2 = asrc[s2];
            }
            float e = a + ad;
            e = (e >= 0.f) ? e : NEG_SLOPE * e;
            float p = valid ? __expf(e) : 0.f;
            psum += p;
#pragma unroll
            for (int k = 0; k < 16; k++) {
                float pk = __shfl(p, k, 16);
                int   sk = __shfl(s, k, 16);
                acc += pk * (float)h_t[(long long)sk * 16 + lane];
            }
            if (jn >= r1) break;
            j = jn; s = s2; a = a2; valid = validn;
        }
    }
    for (int off = 8; off > 0; off >>= 1) psum += __shfl_xor(psum, off, 16);
    epilogue(d, acc / fmaxf(psum, 1e-16f));
}

// gat + bias/relu + NEXT-layer transform fused in-register
template <int FN>
__global__ void k_gat_ft(const int* __restrict__ rowptr, const int* __restrict__ csr_src,
                         const float* __restrict__ asrc, const float* __restrict__ adst,
                         const _Float16* __restrict__ h_t, const float* __restrict__ bias,
                         const float* __restrict__ Wn, const float* __restrict__ an_src,
                         const float* __restrict__ an_dst,
                         _Float16* __restrict__ h_next, float* __restrict__ asrc_n,
                         float* __restrict__ adst_n, int N) {
    __shared__ float sW[16 * FN];
    __shared__ float sa[FN], sd[FN], sb[16];
    for (int i = threadIdx.x; i < 16 * FN; i += blockDim.x) sW[i] = Wn[i];
    if (threadIdx.x < FN) { sa[threadIdx.x] = an_src[threadIdx.x]; sd[threadIdx.x] = an_dst[threadIdx.x]; }
    if (threadIdx.x < 16) sb[threadIdx.x] = bias[threadIdx.x];
    __syncthreads();

    int grp  = (blockIdx.x * blockDim.x + threadIdx.x) >> 4;
    int lane = threadIdx.x & 15;
    if (grp >= N) return;

    gat_core(rowptr, csr_src, asrc, adst, h_t, N, grp, lane,
        [&](int d, float v) {
            v = fmaxf(v + sb[lane], 0.f);
            float acc2 = 0.f;
#pragma unroll
            for (int k = 0; k < 16; k++) {
                float vk = __shfl(v, k, 16);
                if (lane < FN) acc2 += vk * sW[k * FN + lane];
            }
            float c1 = (lane < FN) ? acc2 * sa[lane] : 0.f;
            float c2 = (lane < FN) ? acc2 * sd[lane] : 0.f;
            for (int off = 8; off > 0; off >>= 1) {
                c1 += __shfl_xor(c1, off, 16);
                c2 += __shfl_xor(c2, off, 16);
            }
            h_next[(long long)d * 16 + lane] = (_Float16)((lane < FN) ? acc2 : 0.f);
            if (lane == 0) { asrc_n[d] = c1; adst_n[d] = c2; }
        });
}

// final gat: fp32 out rows of width FOUT (b3 folded into pool)
template <int FOUT>
__global__ void k_gat_last(const int* __restrict__ rowptr, const int* __restrict__ csr_src,
                           const float* __restrict__ asrc, const float* __restrict__ adst,
                           const _Float16* __restrict__ h_t, float* __restrict__ out, int N) {
    int grp  = (blockIdx.x * blockDim.x + threadIdx.x) >> 4;
    int lane = threadIdx.x & 15;
    if (grp >= N) return;
    gat_core(rowptr, csr_src, asrc, adst, h_t, N, grp, lane,
        [&](int d, float v) {
            if (lane < FOUT) out[(long long)d * FOUT + lane] = v;
        });
}

// ---------------- pool + softmax ----------------
__global__ void k_pool(const float* __restrict__ h3, const int* __restrict__ batch,
                       const float* __restrict__ b3, float* __restrict__ out, int N, int C) {
    int g = blockIdx.x;
    int lo = 0, hi = N;
    while (lo < hi) { int mid = (lo + hi) >> 1; if (batch[mid] < g) lo = mid + 1; else hi = mid; }
    int start = lo;
    hi = N;
    while (lo < hi) { int mid = (lo + hi) >> 1; if (batch[mid] < g + 1) lo = mid + 1; else hi = mid; }
    int end = lo;

    float sum[16];
    for (int f = 0; f < C; f++) sum[f] = 0.f;
    for (int n = start + threadIdx.x; n < end; n += blockDim.x) {
        const float* r = h3 + (long long)n * C;
        for (int f = 0; f < C; f++) sum[f] += r[f];
    }
    __shared__ float red[256 * 16];
    for (int f = 0; f < C; f++) red[threadIdx.x * 16 + f] = sum[f];
    __syncthreads();
    for (int str = blockDim.x / 2; str > 0; str >>= 1) {
        if ((int)threadIdx.x < str)
            for (int f = 0; f < C; f++) red[threadIdx.x * 16 + f] += red[(threadIdx.x + str) * 16 + f];
        __syncthreads();
    }
    if (threadIdx.x == 0) {
        float cnt = fmaxf((float)(end - start), 1.f);
        float vals[16];
        float mx = -INFINITY;
        for (int f = 0; f < C; f++) { vals[f] = red[f] / cnt + b3[f]; mx = fmaxf(mx, vals[f]); }
        float se = 0.f;
        for (int f = 0; f < C; f++) { vals[f] = __expf(vals[f] - mx); se += vals[f]; }
        for (int f = 0; f < C; f++) out[(long long)g * C + f] = vals[f] / se;
    }
}

extern "C" void kernel_launch(void* const* d_in, const int* in_sizes, int n_in,
                              void* d_out, int out_size, void* d_ws, size_t ws_size,
                              hipStream_t stream) {
    const float* x    = (const float*)d_in[0];
    const int*   eidx = (const int*)d_in[1];
    const int*   batch= (const int*)d_in[2];
    const float* emb  = (const float*)d_in[3];
    const float* W1   = (const float*)d_in[4];
    const float* as1  = (const float*)d_in[5];
    const float* ad1  = (const float*)d_in[6];
    const float* b1   = (const float*)d_in[7];
    const float* W2   = (const float*)d_in[8];
    const float* as2  = (const float*)d_in[9];
    const float* ad2  = (const float*)d_in[10];
    const float* b2   = (const float*)d_in[11];
    const float* W3   = (const float*)d_in[12];
    const float* as3  = (const float*)d_in[13];
    const float* ad3  = (const float*)d_in[14];
    const float* b3   = (const float*)d_in[15];

    const int H = in_sizes[5];          // 16
    const int C = in_sizes[13];         // 10
    const int D = in_sizes[4] / H;      // 50
    const int V = in_sizes[3] / D;      // 128
    const int N = in_sizes[0] / V;      // 100000
    const int E = in_sizes[1] / 2;      // 1600000
    const int G = out_size / C;         // 512
    const int* esrc = eidx;
    const int* edst = eidx + E;
    const int NBUK = (N + 255) >> 8;    // 391 buckets of 256 dsts
    constexpr int B2 = 256;             // scatter blocks; runs ~16 entries = one 64B line
    const int M = NBUK * B2;            // histT elements (100K)

    char* w = (char*)d_ws;
    auto carve = [&](size_t bytes) {
        char* p = w;
        w += (bytes + 255) & ~(size_t)255;
        return p;
    };
    float*     as_a    = (float*)carve((size_t)N * 4);
    float*     ad_a    = (float*)carve((size_t)N * 4);
    float*     as_b    = (float*)carve((size_t)N * 4);
    float*     ad_b    = (float*)carve((size_t)N * 4);
    int*       idx     = (int*)carve((size_t)N * 4);
    int*       rowptr  = (int*)carve((size_t)(N + 1) * 4);
    int*       csr_src = (int*)carve((size_t)E * 4);
    int*       histT   = (int*)carve((size_t)M * 4);
    int*       sexcl   = (int*)carve((size_t)M * 4);
    int*       bsums   = (int*)carve(2048 * 4);
    _Float16*  hTa     = (_Float16*)carve((size_t)N * 16 * 2);
    _Float16*  hTb     = (_Float16*)carve((size_t)N * 16 * 2);
    size_t zone_bytes = ((size_t)E * 4 > (size_t)N * C * 4) ? (size_t)E * 4 : (size_t)N * C * 4;
    char*  zone = carve(zone_bytes);
    float* X0  = (float*)zone;
    int*   tmp = (int*)zone;
    (void)ws_size; (void)n_in;

    const int BT = 256;
    dim3 blk(BT);
    int gGat  = (N * 16 + BT - 1) / BT;     // 16 lanes per dst
    int nb2   = (M + 255) / 256;            // scan blocks over histT (391)
    int gArg  = (N + 31) / 32;              // argmax blocks (32 nodes per 1024-thr block)
    int gTr   = (N + BT - 1) / BT;          // transform blocks

    // ---- K_A: histB + argmax in one launch ----
    k_histarg<B2><<<B2 + gArg, dim3(1024), 0, stream>>>(x, edst, E, histT, NBUK, idx, N, V);

    // ---- K_B: scan1 + layer-1 transform in one launch ----
    k_scan_tr<50, 16><<<nb2 + gTr, blk, 0, stream>>>(histT, sexcl, bsums, M,
                                                     emb, idx, W1, as1, ad1, hTa, as_a, ad_a, N, nb2);
    k_scan2<<<1, 1024, 0, stream>>>(bsums, nb2);

    // ---- scatter + bin ----
    k_scatB<B2><<<B2, dim3(1024), 0, stream>>>(esrc, edst, E, sexcl, bsums, tmp, NBUK);
    k_binB<B2><<<NBUK, blk, 0, stream>>>(sexcl, bsums, tmp, rowptr, csr_src, N, NBUK, E);

    // ---- gat1 (+b1,relu) fused with transform2 -> hTb, a_b ----
    k_gat_ft<16><<<gGat, blk, 0, stream>>>(rowptr, csr_src, as_a, ad_a, hTa, b1,
                                           W2, as2, ad2, hTb, as_b, ad_b, N);

    // ---- gat2 (+b2,relu) fused with transform3 -> hTa, a_a ----
    k_gat_ft<10><<<gGat, blk, 0, stream>>>(rowptr, csr_src, as_b, ad_b, hTb, b2,
                                           W3, as3, ad3, hTa, as_a, ad_a, N);

    // ---- gat3 -> X0 (N x 10 fp32) ----
    k_gat_last<10><<<gGat, blk, 0, stream>>>(rowptr, csr_src, as_a, ad_a, hTa, X0, N);

    // ---- pool + softmax ----
    k_pool<<<G, blk, 0, stream>>>(X0, batch, b3, (float*)d_out, N, C);
}